// Round 1
// baseline (138.412 us; speedup 1.0000x reference)
//
#include <hip/hip_runtime.h>
#include <hip/hip_bf16.h>

#define C_ 384
#define B_ 16
#define H_ 56
#define W_ 56
#define PAD_ 6
#define LW_ 68              // 56 + 2*6
#define PLANE_ (LW_ * LW_)  // 4624 floats
#define NPL_ 4              // planes (same channel, different batch) per block
#define TPB_ 448            // 7 waves; 112 threads per plane (14 xg * 8 yg)

// Fold all 7 branches (conv + BN) into one 13x13 kernel per channel + bias.
// weff layout: [C][13][16] (rows padded to 16 floats for aligned scalar loads)
__global__ void build_weights_kernel(
    const float* __restrict__ lk, const float* __restrict__ obn,
    const float* __restrict__ w5, const float* __restrict__ w7a,
    const float* __restrict__ w7b, const float* __restrict__ w3a,
    const float* __restrict__ w3b, const float* __restrict__ w3c,
    const float* __restrict__ brbn,
    float* __restrict__ weff, float* __restrict__ bias)
{
    int c = blockIdx.x;
    int t = threadIdx.x;

    float sc[7], sh[7];
    {
        float g = obn[c], b = obn[C_ + c], m = obn[2 * C_ + c], v = obn[3 * C_ + c];
        float s = g * rsqrtf(v + 1e-5f);
        sc[0] = s; sh[0] = b - m * s;
    }
#pragma unroll
    for (int i = 0; i < 6; ++i) {
        float g = brbn[(i * 4 + 0) * C_ + c], b = brbn[(i * 4 + 1) * C_ + c];
        float m = brbn[(i * 4 + 2) * C_ + c], v = brbn[(i * 4 + 3) * C_ + c];
        float s = g * rsqrtf(v + 1e-5f);
        sc[i + 1] = s; sh[i + 1] = b - m * s;
    }

    if (t < 13 * 16) {
        int py = t >> 4, px = t & 15;
        float a = 0.f;
        if (px < 13) {
            int dy = py - 6, dx = px - 6;
            a = sc[0] * lk[c * 169 + py * 13 + px];   // 13x13, dil 1
#define ADDBR(Wp, K, R, SI)                                               \
            {                                                             \
                const int half = ((K) - 1) / 2;                           \
                if (dy % (R) == 0 && dx % (R) == 0) {                     \
                    int iy = dy / (R), ix = dx / (R);                     \
                    if (iy >= -half && iy <= half && ix >= -half && ix <= half) \
                        a += sc[SI] * Wp[c * (K) * (K) + (iy + half) * (K) + (ix + half)]; \
                }                                                         \
            }
            ADDBR(w5,  5, 1, 1)
            ADDBR(w7a, 7, 1, 2)
            ADDBR(w7b, 7, 2, 3)
            ADDBR(w3a, 3, 3, 4)
            ADDBR(w3b, 3, 4, 5)
            ADDBR(w3c, 3, 5, 6)
#undef ADDBR
        }
        weff[c * 208 + t] = a;
    }
    if (t == 0) {
        float s = 0.f;
#pragma unroll
        for (int i = 0; i < 7; ++i) s += sh[i];
        bias[c] = s;
    }
}

// One block: 4 planes (batches bg*4..bg*4+3) of channel c.
// Per plane: 112 threads, each computes a 4-wide x 7-tall output tile.
__global__ __launch_bounds__(TPB_) void dwconv13_kernel(
    const float* __restrict__ x, const float* __restrict__ weff,
    const float* __restrict__ bias, float* __restrict__ out)
{
    __shared__ float sx[NPL_ * PLANE_];   // 73984 B

    int bid = blockIdx.x;
    int c  = bid % C_;
    int bg = bid / C_;   // 0..3

    // Stage 4 planes into LDS with zero halo (halo IS the conv padding).
    for (int p = 0; p < NPL_; ++p) {
        const float* xp = x + ((size_t)(bg * NPL_ + p) * C_ + c) * (H_ * W_);
        for (int idx = threadIdx.x; idx < PLANE_; idx += TPB_) {
            int iy = idx / LW_ - PAD_;
            int ix = idx % LW_ - PAD_;
            float v = 0.f;
            if ((unsigned)iy < (unsigned)H_ && (unsigned)ix < (unsigned)W_)
                v = xp[iy * W_ + ix];
            sx[p * PLANE_ + idx] = v;
        }
    }
    __syncthreads();

    const float* wc = weff + c * 208;   // block-uniform -> s_load path
    float bv = bias[c];

    int t   = threadIdx.x;
    int p   = t / 112;
    int rem = t - p * 112;
    int xg  = rem % 14;       // x0 = 4*xg  (16B aligned in LDS and in out)
    int yg  = rem / 14;       // y0 = 7*yg
    int x0 = xg * 4, y0 = yg * 7;
    const float* sp = sx + p * PLANE_;

    float acc[7][4];
#pragma unroll
    for (int i = 0; i < 7; ++i)
#pragma unroll
        for (int j = 0; j < 4; ++j) acc[i][j] = bv;

    // Sliding window over 19 padded input rows; each row read once (4x b128).
#pragma unroll 1
    for (int rr = 0; rr < 19; ++rr) {
        float rin[16];
        const float4* rp = (const float4*)(sp + (y0 + rr) * LW_ + x0);
        *(float4*)(rin + 0)  = rp[0];
        *(float4*)(rin + 4)  = rp[1];
        *(float4*)(rin + 8)  = rp[2];
        *(float4*)(rin + 12) = rp[3];
#pragma unroll
        for (int tt = 0; tt < 7; ++tt) {
            int ky = rr - tt;
            if (ky < 0 || ky > 12) continue;   // uniform scalar branch
            const float* wrow = wc + ky * 16;
#pragma unroll
            for (int kx = 0; kx < 13; ++kx) {
                float w = wrow[kx];
#pragma unroll
                for (int j = 0; j < 4; ++j)
                    acc[tt][j] = fmaf(w, rin[kx + j], acc[tt][j]);
            }
        }
    }

    float* op = out + ((size_t)(bg * NPL_ + p) * C_ + c) * (H_ * W_);
#pragma unroll
    for (int tt = 0; tt < 7; ++tt) {
        float4 v = make_float4(acc[tt][0], acc[tt][1], acc[tt][2], acc[tt][3]);
        *(float4*)(op + (y0 + tt) * W_ + x0) = v;
    }
}

extern "C" void kernel_launch(void* const* d_in, const int* in_sizes, int n_in,
                              void* d_out, int out_size, void* d_ws, size_t ws_size,
                              hipStream_t stream) {
    const float* x    = (const float*)d_in[0];
    const float* lk   = (const float*)d_in[1];
    const float* obn  = (const float*)d_in[2];
    const float* w5   = (const float*)d_in[3];
    const float* w7a  = (const float*)d_in[4];
    const float* w7b  = (const float*)d_in[5];
    const float* w3a  = (const float*)d_in[6];
    const float* w3b  = (const float*)d_in[7];
    const float* w3c  = (const float*)d_in[8];
    const float* brbn = (const float*)d_in[9];
    float* out  = (float*)d_out;

    float* weff = (float*)d_ws;            // 384*208 floats = 319488 B
    float* bias = weff + C_ * 208;         // 384 floats

    hipLaunchKernelGGL(build_weights_kernel, dim3(C_), dim3(256), 0, stream,
                       lk, obn, w5, w7a, w7b, w3a, w3b, w3c, brbn, weff, bias);

    hipLaunchKernelGGL(dwconv13_kernel, dim3((B_ / NPL_) * C_), dim3(TPB_), 0, stream,
                       x, weff, bias, out);
}

// Round 2
// 97.690 us; speedup vs baseline: 1.4168x; 1.4168x over previous
//
#include <hip/hip_runtime.h>
#include <hip/hip_bf16.h>

#define C_ 384
#define B_ 16
#define H_ 56
#define W_ 56
#define PAD_ 6
#define LW_ 68              // 56 + 2*6
#define PLANE_ (LW_ * LW_)  // 4624 floats
#define NPL_ 4              // planes (same channel, different batch) per block
#define TPB_ 448            // 7 waves; 112 threads per plane (14 xg * 8 yg)

// Fold all 7 branches (conv + BN) into one 13x13 kernel per channel + bias.
// weff layout: [C][13][16] (rows padded to 16 floats for aligned scalar loads)
__global__ void build_weights_kernel(
    const float* __restrict__ lk, const float* __restrict__ obn,
    const float* __restrict__ w5, const float* __restrict__ w7a,
    const float* __restrict__ w7b, const float* __restrict__ w3a,
    const float* __restrict__ w3b, const float* __restrict__ w3c,
    const float* __restrict__ brbn,
    float* __restrict__ weff, float* __restrict__ bias)
{
    int c = blockIdx.x;
    int t = threadIdx.x;

    float sc[7], sh[7];
    {
        float g = obn[c], b = obn[C_ + c], m = obn[2 * C_ + c], v = obn[3 * C_ + c];
        float s = g * rsqrtf(v + 1e-5f);
        sc[0] = s; sh[0] = b - m * s;
    }
#pragma unroll
    for (int i = 0; i < 6; ++i) {
        float g = brbn[(i * 4 + 0) * C_ + c], b = brbn[(i * 4 + 1) * C_ + c];
        float m = brbn[(i * 4 + 2) * C_ + c], v = brbn[(i * 4 + 3) * C_ + c];
        float s = g * rsqrtf(v + 1e-5f);
        sc[i + 1] = s; sh[i + 1] = b - m * s;
    }

    if (t < 13 * 16) {
        int py = t >> 4, px = t & 15;
        float a = 0.f;
        if (px < 13) {
            int dy = py - 6, dx = px - 6;
            a = sc[0] * lk[c * 169 + py * 13 + px];   // 13x13, dil 1
#define ADDBR(Wp, K, R, SI)                                               \
            {                                                             \
                const int half = ((K) - 1) / 2;                           \
                if (dy % (R) == 0 && dx % (R) == 0) {                     \
                    int iy = dy / (R), ix = dx / (R);                     \
                    if (iy >= -half && iy <= half && ix >= -half && ix <= half) \
                        a += sc[SI] * Wp[c * (K) * (K) + (iy + half) * (K) + (ix + half)]; \
                }                                                         \
            }
            ADDBR(w5,  5, 1, 1)
            ADDBR(w7a, 7, 1, 2)
            ADDBR(w7b, 7, 2, 3)
            ADDBR(w3a, 3, 3, 4)
            ADDBR(w3b, 3, 4, 5)
            ADDBR(w3c, 3, 5, 6)
#undef ADDBR
        }
        weff[c * 208 + t] = a;
    }
    if (t == 0) {
        float s = 0.f;
#pragma unroll
        for (int i = 0; i < 7; ++i) s += sh[i];
        bias[c] = s;
    }
}

// One block: 4 planes (batches bg*4..bg*4+3) of channel c.
// Per plane: 112 threads, each computes a 4-wide x 7-tall output tile.
__global__ __launch_bounds__(TPB_, 4) void dwconv13_kernel(
    const float* __restrict__ x, const float* __restrict__ weff,
    const float* __restrict__ bias, float* __restrict__ out)
{
    __shared__ float sx[NPL_ * PLANE_];   // 73984 B

    int bid = blockIdx.x;
    int c  = bid % C_;
    int bg = bid / C_;   // 0..3
    int t  = threadIdx.x;

    // ---- Phase A: zero the whole LDS region (halo = conv padding). ----
    // 18496 dwords = 4624 float4 slots; 448 threads -> 10 full + 1 partial.
    {
        float4 z = make_float4(0.f, 0.f, 0.f, 0.f);
        float4* s4 = (float4*)sx;
#pragma unroll
        for (int k = 0; k < 11; ++k) {
            int slot = t + k * TPB_;
            if (k < 10 || slot < (NPL_ * PLANE_) / 4) s4[slot] = z;
        }
    }
    __syncthreads();

    // ---- Phase B: stage interior rows, fully coalesced, batched loads. ----
    // 4 planes * 56 rows * 14 float4-groups = 3136 slots = 7 per thread exactly.
    {
        float4 vv[7];
        int    dd[7];
#pragma unroll
        for (int k = 0; k < 7; ++k) {
            int slot = t + k * TPB_;
            int p    = slot / 784;            // 784 = 56*14
            int rem  = slot - p * 784;
            int iy   = rem / 14;
            int g    = rem - iy * 14;
            const float* xp = x + ((size_t)(bg * NPL_ + p) * C_ + c) * (H_ * W_);
            vv[k] = *(const float4*)(xp + iy * W_ + g * 4);
            dd[k] = p * PLANE_ + (iy + PAD_) * LW_ + PAD_ + g * 4;   // even
        }
#pragma unroll
        for (int k = 0; k < 7; ++k) {
            float2* wp = (float2*)(sx + dd[k]);
            wp[0] = make_float2(vv[k].x, vv[k].y);
            wp[1] = make_float2(vv[k].z, vv[k].w);
        }
    }
    __syncthreads();

    const float* wc = weff + c * 208;   // block-uniform -> s_load path
    float bv = bias[c];

    int p   = t / 112;
    int rem = t - p * 112;
    int xg  = rem % 14;       // x0 = 4*xg  (16B aligned in LDS and in out)
    int yg  = rem / 14;       // y0 = 7*yg
    int x0 = xg * 4, y0 = yg * 7;
    const float* sp = sx + p * PLANE_;

    float acc[7][4];
#pragma unroll
    for (int i = 0; i < 7; ++i)
#pragma unroll
        for (int j = 0; j < 4; ++j) acc[i][j] = bv;

    // Sliding window over 19 padded input rows; each row read once (4x b128).
    // FULL unroll: ky bounds become compile-time, weight s_loads hoist, and
    // next row's ds_reads pipeline under current row's FMA burst.
#pragma unroll
    for (int rr = 0; rr < 19; ++rr) {
        float rin[16];
        const float4* rp = (const float4*)(sp + (y0 + rr) * LW_ + x0);
        *(float4*)(rin + 0)  = rp[0];
        *(float4*)(rin + 4)  = rp[1];
        *(float4*)(rin + 8)  = rp[2];
        *(float4*)(rin + 12) = rp[3];
#pragma unroll
        for (int tt = 0; tt < 7; ++tt) {
            int ky = rr - tt;
            if (ky < 0 || ky > 12) continue;   // compile-time (rr,tt both const)
            const float* wrow = wc + ky * 16;
#pragma unroll
            for (int kx = 0; kx < 13; ++kx) {
                float w = wrow[kx];
#pragma unroll
                for (int j = 0; j < 4; ++j)
                    acc[tt][j] = fmaf(w, rin[kx + j], acc[tt][j]);
            }
        }
    }

    float* op = out + ((size_t)(bg * NPL_ + p) * C_ + c) * (H_ * W_);
#pragma unroll
    for (int tt = 0; tt < 7; ++tt) {
        float4 v = make_float4(acc[tt][0], acc[tt][1], acc[tt][2], acc[tt][3]);
        *(float4*)(op + (y0 + tt) * W_ + x0) = v;
    }
}

extern "C" void kernel_launch(void* const* d_in, const int* in_sizes, int n_in,
                              void* d_out, int out_size, void* d_ws, size_t ws_size,
                              hipStream_t stream) {
    const float* x    = (const float*)d_in[0];
    const float* lk   = (const float*)d_in[1];
    const float* obn  = (const float*)d_in[2];
    const float* w5   = (const float*)d_in[3];
    const float* w7a  = (const float*)d_in[4];
    const float* w7b  = (const float*)d_in[5];
    const float* w3a  = (const float*)d_in[6];
    const float* w3b  = (const float*)d_in[7];
    const float* w3c  = (const float*)d_in[8];
    const float* brbn = (const float*)d_in[9];
    float* out  = (float*)d_out;

    float* weff = (float*)d_ws;            // 384*208 floats = 319488 B
    float* bias = weff + C_ * 208;         // 384 floats

    hipLaunchKernelGGL(build_weights_kernel, dim3(C_), dim3(256), 0, stream,
                       lk, obn, w5, w7a, w7b, w3a, w3b, w3c, brbn, weff, bias);

    hipLaunchKernelGGL(dwconv13_kernel, dim3((B_ / NPL_) * C_), dim3(TPB_), 0, stream,
                       x, weff, bias, out);
}